// Round 3
// baseline (3229.728 us; speedup 1.0000x reference)
//
#include <hip/hip_runtime.h>
#include <hip/hip_bf16.h>

// ---------------------------------------------------------------------------
// StackedLSTM (2-layer, 64 steps) + dropout + classifier, bf16-MFMA design.
//
// Sizes: B=128, T=128, D=512, H=1024, G=4*H=4096, S=64 steps, start=55.
//
// Wavefront-pipelined phases: phase k runs layer0(step k) AND layer1(step
// k-1) concurrently in one 256-block launch (they are independent).
//   phase 0:   L0(0)            [128 blocks]
//   phase 1..63: L0(k) + L1(k-1) [256 blocks, role = blockIdx&1]
//   phase 64:  L1(63)           [128 blocks]
// h0/h1 are ping-ponged by step parity. 67 total launches (vs 131 naive).
//
// Role block owns 8 hidden units (=32 gate cols: 4 gates x 8) of its layer.
// Wave w (of 8) = M-tile w (batch rows w*16..w*16+15). GEMM operands read
// straight from global (weights L2-resident per XCD; role=blockIdx&1 puts
// one role per XCD -> ~3-4MB weight footprint per XCD L2). LDS only for
// the accumulator->epilogue shuffle.
// ---------------------------------------------------------------------------

typedef __attribute__((ext_vector_type(8))) short s8v;   // 8 x bf16 (4 VGPR)
typedef __attribute__((ext_vector_type(4))) float f4v;   // fp32 accum frag
typedef unsigned short bfu;

#define BATCH 128
#define HID   1024
#define NSTEP 64
#define TDIM  128
#define DDIM  512
#define TSTART 55

__device__ __forceinline__ bfu f2bf(float f) {
    union { float f; unsigned int u; } v; v.f = f;
    unsigned int r = (v.u + 0x7FFFu + ((v.u >> 16) & 1u)) >> 16;  // RNE
    return (bfu)r;
}
__device__ __forceinline__ float sigm(float x) {
    return 1.f / (1.f + __expf(-x));
}

// ---------------------------------------------------------------------------
// prep: fp32->bf16 conversion, combined biases, zero-init h/c state.
// hzero = h0a|h0b|h1a|h1b contiguous (4*131072 bf16); czero = c0|c1 (2*131072 f32)
// ---------------------------------------------------------------------------
__global__ void prep_kernel(
    const float* __restrict__ xs,
    const float* __restrict__ Wih0, const float* __restrict__ Whh0,
    const float* __restrict__ Wih1, const float* __restrict__ Whh1,
    const float* __restrict__ Wcls,
    const float* __restrict__ bih0, const float* __restrict__ bhh0,
    const float* __restrict__ bih1, const float* __restrict__ bhh1,
    bfu* __restrict__ xbf, bfu* __restrict__ wih0b, bfu* __restrict__ whh0b,
    bfu* __restrict__ wih1b, bfu* __restrict__ whh1b, bfu* __restrict__ wclsb,
    float* __restrict__ bias0, float* __restrict__ bias1,
    bfu* __restrict__ hzero, float* __restrict__ czero)
{
    const size_t NX  = (size_t)NSTEP * BATCH * DDIM;         // 4,194,304
    const size_t E1  = NX  + (size_t)4096 * 512;             // +wih0
    const size_t E2  = E1  + (size_t)4096 * 1024;            // +whh0
    const size_t E3  = E2  + (size_t)4096 * 1024;            // +wih1
    const size_t E4  = E3  + (size_t)4096 * 1024;            // +whh1
    const size_t E5  = E4  + (size_t)1000 * 1024;            // +wcls
    const size_t E6  = E5  + 4096;                           // bias0
    const size_t E7  = E6  + 4096;                           // bias1
    const size_t E8  = E7  + (size_t)4 * BATCH * HID;        // h0a,h0b,h1a,h1b
    const size_t E9  = E8  + (size_t)2 * BATCH * HID;        // c0,c1

    size_t stride = (size_t)gridDim.x * blockDim.x;
    for (size_t i = (size_t)blockIdx.x * blockDim.x + threadIdx.x; i < E9; i += stride) {
        if (i < NX) {
            size_t t = i / ((size_t)BATCH * DDIM);
            size_t b = (i / DDIM) % BATCH;
            size_t k = i % DDIM;
            xbf[i] = f2bf(xs[b * ((size_t)TDIM * DDIM) + (TSTART + t) * DDIM + k]);
        } else if (i < E1) { size_t j = i - NX;  wih0b[j] = f2bf(Wih0[j]); }
        else if (i < E2)   { size_t j = i - E1;  whh0b[j] = f2bf(Whh0[j]); }
        else if (i < E3)   { size_t j = i - E2;  wih1b[j] = f2bf(Wih1[j]); }
        else if (i < E4)   { size_t j = i - E3;  whh1b[j] = f2bf(Whh1[j]); }
        else if (i < E5)   { size_t j = i - E4;  wclsb[j] = f2bf(Wcls[j]); }
        else if (i < E6)   { size_t j = i - E5;  bias0[j] = bih0[j] + bhh0[j]; }
        else if (i < E7)   { size_t j = i - E6;  bias1[j] = bih1[j] + bhh1[j]; }
        else if (i < E8)   { hzero[i - E7] = 0; }
        else               { czero[i - E8] = 0.f; }
    }
}

// ---------------------------------------------------------------------------
// One LSTM layer: gates = A1@W1^T + A2@W2^T (+bias), fused cell update.
// A1/W1 row stride = K1 (x:512, h:1024). A2/W2 stride = 1024, K2 = 1024.
// Block owns 8 hidden units n0..n0+7 -> 32 gate cols as 2 N-tiles of 16:
//   local col c in [0,32): j = (c>>3)*1024 + n0 + (c&7)
// Wave w (of 8) = M-tile w. D layout (m89/m91): row = w*16+kg*4+r, col = lr.
// ---------------------------------------------------------------------------
template<int K1>
__device__ __forceinline__ void layer_body(
    const bfu* __restrict__ A1, const bfu* __restrict__ W1,
    const bfu* __restrict__ A2, const bfu* __restrict__ W2,
    const float* __restrict__ bias, float* __restrict__ c_state,
    bfu* __restrict__ h_out, float* __restrict__ h_out_f32,
    int n0, int tid, float (*eps)[33])
{
    const int l   = tid & 63;
    const int w   = tid >> 6;        // wave id == M-tile
    const int lr  = l & 15;          // A-row / B-col within tile
    const int kg  = l >> 4;          // k-group (8 consecutive k each)

    const int c1l = 16 + lr;
    const int j0  = (lr  >> 3) * HID + n0 + (lr  & 7);   // N-tile 0 (gates i,f)
    const int j1  = (c1l >> 3) * HID + n0 + (c1l & 7);   // N-tile 1 (gates g,o)
    const int arow = w * 16 + lr;

    f4v acc0 = {0.f, 0.f, 0.f, 0.f};
    f4v acc1 = {0.f, 0.f, 0.f, 0.f};

    {   // phase 1: A1 @ W1^T  (K = K1, strides K1)
        const bfu* ap  = A1 + (size_t)arow * K1 + kg * 8;
        const bfu* bp0 = W1 + (size_t)j0 * K1 + kg * 8;
        const bfu* bp1 = W1 + (size_t)j1 * K1 + kg * 8;
        #pragma unroll 8
        for (int kk = 0; kk < K1; kk += 32) {
            s8v a  = *(const s8v*)ap;
            s8v b0 = *(const s8v*)bp0;
            s8v b1 = *(const s8v*)bp1;
            acc0 = __builtin_amdgcn_mfma_f32_16x16x32_bf16(a, b0, acc0, 0, 0, 0);
            acc1 = __builtin_amdgcn_mfma_f32_16x16x32_bf16(a, b1, acc1, 0, 0, 0);
            ap += 32; bp0 += 32; bp1 += 32;
        }
    }
    {   // phase 2: A2 @ W2^T  (K = 1024, strides 1024)
        const bfu* ap  = A2 + (size_t)arow * 1024 + kg * 8;
        const bfu* bp0 = W2 + (size_t)j0 * 1024 + kg * 8;
        const bfu* bp1 = W2 + (size_t)j1 * 1024 + kg * 8;
        #pragma unroll 8
        for (int kk = 0; kk < 1024; kk += 32) {
            s8v a  = *(const s8v*)ap;
            s8v b0 = *(const s8v*)bp0;
            s8v b1 = *(const s8v*)bp1;
            acc0 = __builtin_amdgcn_mfma_f32_16x16x32_bf16(a, b0, acc0, 0, 0, 0);
            acc1 = __builtin_amdgcn_mfma_f32_16x16x32_bf16(a, b1, acc1, 0, 0, 0);
            ap += 32; bp0 += 32; bp1 += 32;
        }
    }

    {
        const int rbase = w * 16 + kg * 4;
        #pragma unroll
        for (int r = 0; r < 4; ++r) {
            eps[rbase + r][lr]      = acc0[r];
            eps[rbase + r][16 + lr] = acc1[r];
        }
    }
    __syncthreads();

    // fused LSTM epilogue: 1024 (row,u) items over 512 threads
    #pragma unroll
    for (int it = tid; it < BATCH * 8; it += 512) {
        const int row = it >> 3;
        const int u   = it & 7;
        const int n   = n0 + u;
        float gi = eps[row][u]      + bias[n];
        float gf = eps[row][8 + u]  + bias[HID + n];
        float gg = eps[row][16 + u] + bias[2 * HID + n];
        float go = eps[row][24 + u] + bias[3 * HID + n];
        float cold = c_state[row * HID + n];
        float cnew = sigm(gf) * cold + sigm(gi) * tanhf(gg);
        float hnew = sigm(go) * tanhf(cnew);
        c_state[row * HID + n] = cnew;
        h_out[(size_t)row * HID + n] = f2bf(hnew);
        if (h_out_f32) h_out_f32[row * HID + n] = hnew;
    }
}

// ---------------------------------------------------------------------------
// phase kernel: mode 0 = both roles (grid 256), 1 = L0 only, 2 = L1 only
// (grid 128). Slot algebra (j = k-1 is L1's step):
//   L0(k): reads h0[(k-1)&1], writes h0[k&1]
//   L1(j): reads h0[j&1] = h0[(k-1)&1], h1[(j-1)&1] = h1[k&1];
//          writes h1[j&1] = h1[(k+1)&1]  (note (k-1)&1 == (k+1)&1)
// ---------------------------------------------------------------------------
__global__ __launch_bounds__(512)
void phase_kernel(
    const bfu* __restrict__ xbf,
    const bfu* __restrict__ wih0, const bfu* __restrict__ whh0,
    const bfu* __restrict__ wih1, const bfu* __restrict__ whh1,
    const float* __restrict__ bias0, const float* __restrict__ bias1,
    float* __restrict__ c0, float* __restrict__ c1,
    bfu* __restrict__ h0a, bfu* __restrict__ h0b,
    bfu* __restrict__ h1a, bfu* __restrict__ h1b,
    float* __restrict__ h1f, int k, int mode)
{
    __shared__ float eps[128][33];   // +1 pad: epilogue reads stride-1 in u

    int role, n0;
    if (mode == 0) { role = blockIdx.x & 1; n0 = (blockIdx.x >> 1) * 8; }
    else           { role = mode - 1;       n0 = blockIdx.x * 8; }

    bfu* h0s[2] = { h0a, h0b };
    bfu* h1s[2] = { h1a, h1b };
    const bfu* h0_prev = h0s[(k + 1) & 1];   // h0(k-1)
    bfu*       h0_cur  = h0s[k & 1];         // h0(k)
    const bfu* h1_prev = h1s[k & 1];         // h1(k-2)
    bfu*       h1_cur  = h1s[(k + 1) & 1];   // h1(k-1)

    if (role == 0) {
        layer_body<512>(xbf + (size_t)k * BATCH * DDIM, wih0,
                        h0_prev, whh0, bias0, c0, h0_cur, nullptr,
                        n0, threadIdx.x, eps);
    } else {
        layer_body<1024>(h0_prev, wih1,
                         h1_prev, whh1, bias1, c1, h1_cur, h1f,
                         n0, threadIdx.x, eps);
    }
}

// ---------------------------------------------------------------------------
// classifier with fused dropout: out = (mask(h1)/0.5) @ Wcls^T + b_cls
// 63 blocks x 16 cols, 8 waves = M-tiles. A-frags built in-register from
// f32 h1 + dropout mask.
// ---------------------------------------------------------------------------
__global__ __launch_bounds__(512)
void cls_kernel(const float* __restrict__ h1f, const float* __restrict__ du,
                const bfu* __restrict__ Wc, const float* __restrict__ bc,
                float* __restrict__ out)
{
    const int tid = threadIdx.x;
    const int l   = tid & 63;
    const int w   = tid >> 6;
    const int lr  = l & 15;
    const int kg  = l >> 4;
    const int j   = blockIdx.x * 16 + lr;
    const int jW  = (j < 1000) ? j : 999;   // clamp to stay in-bounds

    f4v acc = {0.f, 0.f, 0.f, 0.f};
    const float* hp = h1f + (size_t)(w * 16 + lr) * HID + kg * 8;
    const float* dp = du  + (size_t)(w * 16 + lr) * HID + kg * 8;
    const bfu*   bp = Wc  + (size_t)jW * HID + kg * 8;
    #pragma unroll 4
    for (int kk = 0; kk < HID; kk += 32) {
        f4v h0v = *(const f4v*)hp;
        f4v h1v = *(const f4v*)(hp + 4);
        f4v d0v = *(const f4v*)dp;
        f4v d1v = *(const f4v*)(dp + 4);
        s8v a;
        #pragma unroll
        for (int e = 0; e < 4; ++e) {
            a[e]     = (short)f2bf(d0v[e] > 0.5f ? h0v[e] * 2.f : 0.f);
            a[4 + e] = (short)f2bf(d1v[e] > 0.5f ? h1v[e] * 2.f : 0.f);
        }
        s8v b = *(const s8v*)bp;
        acc = __builtin_amdgcn_mfma_f32_16x16x32_bf16(a, b, acc, 0, 0, 0);
        hp += 32; dp += 32; bp += 32;
    }
    if (j < 1000) {
        const float bj = bc[j];
        const int rbase = w * 16 + kg * 4;
        #pragma unroll
        for (int r = 0; r < 4; ++r)
            out[(size_t)(rbase + r) * 1000 + j] = acc[r] + bj;
    }
}

// ---------------------------------------------------------------------------
extern "C" void kernel_launch(void* const* d_in, const int* in_sizes, int n_in,
                              void* d_out, int out_size, void* d_ws, size_t ws_size,
                              hipStream_t stream)
{
    const float* xs   = (const float*)d_in[0];
    const float* Wih0 = (const float*)d_in[1];
    const float* Whh0 = (const float*)d_in[2];
    const float* bih0 = (const float*)d_in[3];
    const float* bhh0 = (const float*)d_in[4];
    const float* Wih1 = (const float*)d_in[5];
    const float* Whh1 = (const float*)d_in[6];
    const float* bih1 = (const float*)d_in[7];
    const float* bhh1 = (const float*)d_in[8];
    const float* Wcls = (const float*)d_in[9];
    const float* bcls = (const float*)d_in[10];
    const float* du   = (const float*)d_in[11];
    float* out = (float*)d_out;

    // ws carve-out (256B-aligned; every size is already a 256B multiple,
    // so h0a..h1b and c0..c1 are contiguous for prep's zero-fill). ~26 MB.
    char* p = (char*)d_ws;
    auto alloc = [&](size_t bytes) {
        char* r = p; p += (bytes + 255) & ~(size_t)255; return r;
    };
    bfu*   xbf   = (bfu*)  alloc((size_t)NSTEP * BATCH * DDIM * 2);
    bfu*   wih0b = (bfu*)  alloc((size_t)4096 * 512 * 2);
    bfu*   whh0b = (bfu*)  alloc((size_t)4096 * 1024 * 2);
    bfu*   wih1b = (bfu*)  alloc((size_t)4096 * 1024 * 2);
    bfu*   whh1b = (bfu*)  alloc((size_t)4096 * 1024 * 2);
    bfu*   wclsb = (bfu*)  alloc((size_t)1000 * 1024 * 2);
    float* bias0 = (float*)alloc(4096 * 4);
    float* bias1 = (float*)alloc(4096 * 4);
    bfu*   h0a   = (bfu*)  alloc((size_t)BATCH * HID * 2);
    bfu*   h0b   = (bfu*)  alloc((size_t)BATCH * HID * 2);
    bfu*   h1a   = (bfu*)  alloc((size_t)BATCH * HID * 2);
    bfu*   h1b   = (bfu*)  alloc((size_t)BATCH * HID * 2);
    float* c0    = (float*)alloc((size_t)BATCH * HID * 4);
    float* c1    = (float*)alloc((size_t)BATCH * HID * 4);
    float* h1f   = (float*)alloc((size_t)BATCH * HID * 4);
    (void)ws_size; (void)in_sizes; (void)n_in; (void)out_size;

    prep_kernel<<<2048, 256, 0, stream>>>(
        xs, Wih0, Whh0, Wih1, Whh1, Wcls, bih0, bhh0, bih1, bhh1,
        xbf, wih0b, whh0b, wih1b, whh1b, wclsb, bias0, bias1,
        h0a /*hzero base*/, c0 /*czero base*/);

    // phase 0: L0(0) only
    phase_kernel<<<128, 512, 0, stream>>>(
        xbf, wih0b, whh0b, wih1b, whh1b, bias0, bias1, c0, c1,
        h0a, h0b, h1a, h1b, h1f, 0, 1);
    // phases 1..63: L0(k) + L1(k-1)
    for (int k = 1; k < NSTEP; ++k) {
        phase_kernel<<<256, 512, 0, stream>>>(
            xbf, wih0b, whh0b, wih1b, whh1b, bias0, bias1, c0, c1,
            h0a, h0b, h1a, h1b, h1f, k, 0);
    }
    // phase 64: L1(63) only
    phase_kernel<<<128, 512, 0, stream>>>(
        xbf, wih0b, whh0b, wih1b, whh1b, bias0, bias1, c0, c1,
        h0a, h0b, h1a, h1b, h1f, NSTEP, 2);

    cls_kernel<<<63, 512, 0, stream>>>(h1f, du, wclsb, bcls, out);
}

// Round 4
// 2560.302 us; speedup vs baseline: 1.2615x; 1.2615x over previous
//
#include <hip/hip_runtime.h>
#include <hip/hip_bf16.h>
#include <hip/hip_cooperative_groups.h>

namespace cg = cooperative_groups;

// ---------------------------------------------------------------------------
// StackedLSTM (2-layer, 64 steps) + dropout + classifier on MI355X.
//
// Single persistent cooperative kernel (256 blocks x 512 thr, 1 block/CU):
//   - weights permuted into LDS ONCE (frag-linear -> conflict-free ds_read_b128)
//   - x and h kept in global in FRAG-PERMUTED layout -> A-loads are fully
//     coalesced 1KB global_load_dwordx4 (kills the 16-line scatter of r3)
//   - cell state + biases live in registers across all 64 steps
//   - wavefront pipelining: phase p runs L0(p) on even blocks, L1(p-1) on
//     odd blocks; grid.sync() between phases (64 syncs = serial depth).
//
// Frag layout for an [R=128][K] bf16 matrix (MFMA 16x16x32, verified m89/m91):
//   chunk = (row>>4)*(K/32) + (k>>5)          (1KB chunks: 16 rows x 32 k)
//   lane  = ((k>>3)&3)*16 + (row&15)
//   elem  = k&7          addr = chunk*512 + lane*8 + elem   (elements)
// Lane l of wave w reading chunk w*(K/32)+kk gets exactly row w*16+(l&15),
// k = kk*32+(l>>4)*8.. — identical operands to the r3-verified kernel, so
// numerics are bit-identical (absmax stays ~9.8e-4).
// ---------------------------------------------------------------------------

typedef __attribute__((ext_vector_type(8))) short s8v;   // 8 x bf16 (4 VGPR)
typedef __attribute__((ext_vector_type(4))) float f4v;   // fp32 accum frag
typedef unsigned short bfu;

#define BATCH 128
#define HID   1024
#define NSTEP 64
#define TDIM  128
#define DDIM  512
#define TSTART 55

__device__ __forceinline__ bfu f2bf(float f) {
    union { float f; unsigned int u; } v; v.f = f;
    unsigned int r = (v.u + 0x7FFFu + ((v.u >> 16) & 1u)) >> 16;  // RNE
    return (bfu)r;
}
__device__ __forceinline__ float sigm(float x) {
    return 1.f / (1.f + __expf(-x));
}

// ---------------------------------------------------------------------------
// prep: fp32->bf16 conversion (x into per-step frag layout), combined biases,
// zero-init h ping-pong buffers (h0a|h0b|h1a|h1b contiguous).
// ---------------------------------------------------------------------------
__global__ void prep_kernel(
    const float* __restrict__ xs,
    const float* __restrict__ Wih0, const float* __restrict__ Whh0,
    const float* __restrict__ Wih1, const float* __restrict__ Whh1,
    const float* __restrict__ Wcls,
    const float* __restrict__ bih0, const float* __restrict__ bhh0,
    const float* __restrict__ bih1, const float* __restrict__ bhh1,
    bfu* __restrict__ xbf, bfu* __restrict__ wih0b, bfu* __restrict__ whh0b,
    bfu* __restrict__ wih1b, bfu* __restrict__ whh1b, bfu* __restrict__ wclsb,
    float* __restrict__ bias0, float* __restrict__ bias1,
    bfu* __restrict__ hzero)
{
    const size_t NX  = (size_t)NSTEP * BATCH * DDIM;         // 4,194,304
    const size_t E1  = NX  + (size_t)4096 * 512;             // +wih0
    const size_t E2  = E1  + (size_t)4096 * 1024;            // +whh0
    const size_t E3  = E2  + (size_t)4096 * 1024;            // +wih1
    const size_t E4  = E3  + (size_t)4096 * 1024;            // +whh1
    const size_t E5  = E4  + (size_t)1000 * 1024;            // +wcls
    const size_t E6  = E5  + 4096;                           // bias0
    const size_t E7  = E6  + 4096;                           // bias1
    const size_t E8  = E7  + (size_t)4 * BATCH * HID;        // h0a,h0b,h1a,h1b

    size_t stride = (size_t)gridDim.x * blockDim.x;
    for (size_t i = (size_t)blockIdx.x * blockDim.x + threadIdx.x; i < E8; i += stride) {
        if (i < NX) {
            // destination is frag-permuted within each 65536-element step
            size_t t   = i >> 16;
            int    rem = (int)(i & 65535);
            int chunk = rem >> 9;          // 1KB chunk (512 elems)
            int le    = rem & 511;
            int l = le >> 3, e = le & 7;
            int m  = chunk >> 4;           // K=512 -> 16 chunks per M-tile
            int kk = chunk & 15;
            int row = m * 16 + (l & 15);
            int k   = kk * 32 + (l >> 4) * 8 + e;
            xbf[i] = f2bf(xs[(size_t)row * (TDIM * DDIM) + (TSTART + t) * DDIM + k]);
        } else if (i < E1) { size_t j = i - NX;  wih0b[j] = f2bf(Wih0[j]); }
        else if (i < E2)   { size_t j = i - E1;  whh0b[j] = f2bf(Whh0[j]); }
        else if (i < E3)   { size_t j = i - E2;  wih1b[j] = f2bf(Wih1[j]); }
        else if (i < E4)   { size_t j = i - E3;  whh1b[j] = f2bf(Whh1[j]); }
        else if (i < E5)   { size_t j = i - E4;  wclsb[j] = f2bf(Wcls[j]); }
        else if (i < E6)   { size_t j = i - E5;  bias0[j] = bih0[j] + bhh0[j]; }
        else if (i < E7)   { size_t j = i - E6;  bias1[j] = bih1[j] + bhh1[j]; }
        else               { hzero[i - E7] = 0; }
    }
}

// ---------------------------------------------------------------------------
// One layer-step inside the persistent kernel.
// A1/A2: frag-permuted global (A1 has CH1 chunks/M-tile, A2 has 32).
// W in LDS, frag-linear, chunk order: [G1 NT0: CH1][G1 NT1: CH1][G2 NT0: 32][G2 NT1: 32]
// ---------------------------------------------------------------------------
template<int CH1>
__device__ __forceinline__ void layer_step(
    const bfu* __restrict__ A1, const bfu* __restrict__ A2,
    const bfu* __restrict__ wlds, float (*eps)[33],
    bfu* __restrict__ h_out, float* __restrict__ h_out_f32,
    int tid, int n0,
    float bgi, float bgf, float bgg, float bgo,
    float& c_a, float& c_b)
{
    const int l  = tid & 63;
    const int w  = tid >> 6;       // wave id == M-tile
    const int lr = l & 15;
    const int kg = l >> 4;

    f4v acc0 = {0.f, 0.f, 0.f, 0.f};
    f4v acc1 = {0.f, 0.f, 0.f, 0.f};

    {   // GEMM1: A1 @ W1^T   (CH1 chunks)
        const bfu* ap  = A1 + (size_t)(w * CH1) * 512 + l * 8;
        const bfu* b0p = wlds + l * 8;                          // chunks 0..CH1-1
        const bfu* b1p = wlds + (size_t)CH1 * 512 + l * 8;      // chunks CH1..2CH1-1
        #pragma unroll 8
        for (int kk = 0; kk < CH1; ++kk) {
            s8v a  = *(const s8v*)ap;  ap  += 512;
            s8v b0 = *(const s8v*)b0p; b0p += 512;
            s8v b1 = *(const s8v*)b1p; b1p += 512;
            acc0 = __builtin_amdgcn_mfma_f32_16x16x32_bf16(a, b0, acc0, 0, 0, 0);
            acc1 = __builtin_amdgcn_mfma_f32_16x16x32_bf16(a, b1, acc1, 0, 0, 0);
        }
    }
    {   // GEMM2: A2 @ W2^T   (32 chunks, K=1024)
        const bfu* ap  = A2 + (size_t)(w * 32) * 512 + l * 8;
        const bfu* b0p = wlds + (size_t)(2 * CH1) * 512 + l * 8;
        const bfu* b1p = wlds + (size_t)(2 * CH1 + 32) * 512 + l * 8;
        #pragma unroll 8
        for (int kk = 0; kk < 32; ++kk) {
            s8v a  = *(const s8v*)ap;  ap  += 512;
            s8v b0 = *(const s8v*)b0p; b0p += 512;
            s8v b1 = *(const s8v*)b1p; b1p += 512;
            acc0 = __builtin_amdgcn_mfma_f32_16x16x32_bf16(a, b0, acc0, 0, 0, 0);
            acc1 = __builtin_amdgcn_mfma_f32_16x16x32_bf16(a, b1, acc1, 0, 0, 0);
        }
    }

    // D layout: row = w*16 + kg*4 + r, col = lr
    {
        const int rbase = w * 16 + kg * 4;
        #pragma unroll
        for (int r = 0; r < 4; ++r) {
            eps[rbase + r][lr]      = acc0[r];
            eps[rbase + r][16 + lr] = acc1[r];
        }
    }
    __syncthreads();

    // fused LSTM epilogue: 2 items/thread, fixed (row,u) across all steps
    const int u = tid & 7;
    const int n = n0 + u;
    const int hc_lo = ((n >> 5)) * 512 + (((n >> 3) & 3) * 16) * 8 + (n & 7); // chunk/lane const part
    #pragma unroll
    for (int half = 0; half < 2; ++half) {
        const int row = (tid >> 3) + half * 64;
        float gi = eps[row][u]      + bgi;
        float gf = eps[row][8 + u]  + bgf;
        float gg = eps[row][16 + u] + bgg;
        float go = eps[row][24 + u] + bgo;
        float& cc = half ? c_b : c_a;
        float cnew = sigm(gf) * cc + sigm(gi) * tanhf(gg);
        float hnew = sigm(go) * tanhf(cnew);
        cc = cnew;
        // frag-permuted h write (K=1024 -> 32 chunks per M-tile)
        const int idx = hc_lo + (row >> 4) * (32 * 512) + (row & 15) * 8;
        h_out[idx] = f2bf(hnew);
        if (h_out_f32) h_out_f32[(size_t)row * HID + n] = hnew;
    }
    // next phase's eps writes are ordered behind grid.sync()
}

// ---------------------------------------------------------------------------
// Persistent cooperative kernel. 256 blocks: even = layer0, odd = layer1.
// Block owns 8 hidden units (n0..n0+7 -> 32 gate cols as 2 N-tiles of 16).
// LDS: W slice 96/128KB (frag-linear) + eps 16.9KB  => 1 block/CU.
// ---------------------------------------------------------------------------
__global__ __launch_bounds__(512)
void persist_kernel(
    const bfu* __restrict__ xbf,
    const bfu* __restrict__ wih0, const bfu* __restrict__ whh0,
    const bfu* __restrict__ wih1, const bfu* __restrict__ whh1,
    const float* __restrict__ bias0, const float* __restrict__ bias1,
    bfu* __restrict__ h0a, bfu* __restrict__ h0b,
    bfu* __restrict__ h1a, bfu* __restrict__ h1b,
    float* __restrict__ h1f)
{
    __shared__ bfu   wlds[65536];        // 128 KB
    __shared__ float eps[128][33];       // 16.9 KB (+1 pad)

    const int tid  = threadIdx.x;
    const int role = blockIdx.x & 1;
    const int n0   = (blockIdx.x >> 1) * 8;

    const bfu*   W1   = role ? wih1 : wih0;
    const bfu*   W2   = role ? whh1 : whh0;
    const float* bias = role ? bias1 : bias0;
    const int    K1   = role ? 1024 : 512;
    const int    CH1  = K1 >> 5;

    // ---- stage weights into LDS, permuting to frag-linear (once) ----
    {
        const int units = (2 * CH1 + 64) * 64;   // 16B transfers
        for (int u0 = tid; u0 < units; u0 += 512) {
            const int c = u0 >> 6, l = u0 & 63;
            const int lr = l & 15, kg = l >> 4;
            const bfu* Wsrc; int K, nt, kk;
            if (c < 2 * CH1) { Wsrc = W1; K = K1;   nt = c / CH1; kk = c % CH1; }
            else { const int c2 = c - 2 * CH1; Wsrc = W2; K = 1024; nt = c2 >> 5; kk = c2 & 31; }
            const int cl = nt * 16 + lr;
            const int j  = (cl >> 3) * HID + n0 + (cl & 7);
            s8v v = *(const s8v*)(Wsrc + (size_t)j * K + kk * 32 + kg * 8);
            *(s8v*)(wlds + (size_t)c * 512 + l * 8) = v;
        }
    }
    __syncthreads();

    // ---- persistent per-thread epilogue state (biases, cell) ----
    const int n = n0 + (tid & 7);
    const float bgi = bias[n];
    const float bgf = bias[HID + n];
    const float bgg = bias[2 * HID + n];
    const float bgo = bias[3 * HID + n];
    float c_a = 0.f, c_b = 0.f;

    cg::grid_group grid = cg::this_grid();

    // ---- wavefront-pipelined time loop ----
    for (int p = 0; p <= NSTEP; ++p) {
        const bfu* h0_prev = (p & 1) ? h0a : h0b;   // h0s[(p+1)&1]
        bfu*       h0_cur  = (p & 1) ? h0b : h0a;   // h0s[p&1]
        const bfu* h1_prev = (p & 1) ? h1b : h1a;   // h1s[p&1]
        bfu*       h1_cur  = (p & 1) ? h1a : h1b;   // h1s[(p+1)&1]

        if (role == 0) {
            if (p < NSTEP)
                layer_step<16>(xbf + (size_t)p * BATCH * DDIM, h0_prev, wlds, eps,
                               h0_cur, nullptr, tid, n0, bgi, bgf, bgg, bgo, c_a, c_b);
        } else {
            if (p >= 1)
                layer_step<32>(h0_prev, h1_prev, wlds, eps,
                               h1_cur, (p == NSTEP) ? h1f : nullptr,
                               tid, n0, bgi, bgf, bgg, bgo, c_a, c_b);
        }
        grid.sync();
    }
}

// ---------------------------------------------------------------------------
// classifier with fused dropout: out = (mask(h1)/0.5) @ Wcls^T + b_cls
// ---------------------------------------------------------------------------
__global__ __launch_bounds__(512)
void cls_kernel(const float* __restrict__ h1f, const float* __restrict__ du,
                const bfu* __restrict__ Wc, const float* __restrict__ bc,
                float* __restrict__ out)
{
    const int tid = threadIdx.x;
    const int l   = tid & 63;
    const int w   = tid >> 6;
    const int lr  = l & 15;
    const int kg  = l >> 4;
    const int j   = blockIdx.x * 16 + lr;
    const int jW  = (j < 1000) ? j : 999;   // clamp to stay in-bounds

    f4v acc = {0.f, 0.f, 0.f, 0.f};
    const float* hp = h1f + (size_t)(w * 16 + lr) * HID + kg * 8;
    const float* dp = du  + (size_t)(w * 16 + lr) * HID + kg * 8;
    const bfu*   bp = Wc  + (size_t)jW * HID + kg * 8;
    #pragma unroll 4
    for (int kk = 0; kk < HID; kk += 32) {
        f4v h0v = *(const f4v*)hp;
        f4v h1v = *(const f4v*)(hp + 4);
        f4v d0v = *(const f4v*)dp;
        f4v d1v = *(const f4v*)(dp + 4);
        s8v a;
        #pragma unroll
        for (int e = 0; e < 4; ++e) {
            a[e]     = (short)f2bf(d0v[e] > 0.5f ? h0v[e] * 2.f : 0.f);
            a[4 + e] = (short)f2bf(d1v[e] > 0.5f ? h1v[e] * 2.f : 0.f);
        }
        s8v b = *(const s8v*)bp;
        acc = __builtin_amdgcn_mfma_f32_16x16x32_bf16(a, b, acc, 0, 0, 0);
        hp += 32; dp += 32; bp += 32;
    }
    if (j < 1000) {
        const float bj = bc[j];
        const int rbase = w * 16 + kg * 4;
        #pragma unroll
        for (int r = 0; r < 4; ++r)
            out[(size_t)(rbase + r) * 1000 + j] = acc[r] + bj;
    }
}

// ---------------------------------------------------------------------------
extern "C" void kernel_launch(void* const* d_in, const int* in_sizes, int n_in,
                              void* d_out, int out_size, void* d_ws, size_t ws_size,
                              hipStream_t stream)
{
    const float* xs   = (const float*)d_in[0];
    const float* Wih0 = (const float*)d_in[1];
    const float* Whh0 = (const float*)d_in[2];
    const float* bih0 = (const float*)d_in[3];
    const float* bhh0 = (const float*)d_in[4];
    const float* Wih1 = (const float*)d_in[5];
    const float* Whh1 = (const float*)d_in[6];
    const float* bih1 = (const float*)d_in[7];
    const float* bhh1 = (const float*)d_in[8];
    const float* Wcls = (const float*)d_in[9];
    const float* bcls = (const float*)d_in[10];
    const float* du   = (const float*)d_in[11];
    float* out = (float*)d_out;

    // ws carve-out (256B-aligned; h0a..h1b contiguous for prep zero-fill)
    char* p = (char*)d_ws;
    auto alloc = [&](size_t bytes) {
        char* r = p; p += (bytes + 255) & ~(size_t)255; return r;
    };
    bfu*   xbf   = (bfu*)  alloc((size_t)NSTEP * BATCH * DDIM * 2);
    bfu*   wih0b = (bfu*)  alloc((size_t)4096 * 512 * 2);
    bfu*   whh0b = (bfu*)  alloc((size_t)4096 * 1024 * 2);
    bfu*   wih1b = (bfu*)  alloc((size_t)4096 * 1024 * 2);
    bfu*   whh1b = (bfu*)  alloc((size_t)4096 * 1024 * 2);
    bfu*   wclsb = (bfu*)  alloc((size_t)1000 * 1024 * 2);
    float* bias0 = (float*)alloc(4096 * 4);
    float* bias1 = (float*)alloc(4096 * 4);
    bfu*   h0a   = (bfu*)  alloc((size_t)BATCH * HID * 2);
    bfu*   h0b   = (bfu*)  alloc((size_t)BATCH * HID * 2);
    bfu*   h1a   = (bfu*)  alloc((size_t)BATCH * HID * 2);
    bfu*   h1b   = (bfu*)  alloc((size_t)BATCH * HID * 2);
    float* h1f   = (float*)alloc((size_t)BATCH * HID * 4);
    (void)ws_size; (void)in_sizes; (void)n_in; (void)out_size;

    prep_kernel<<<2048, 256, 0, stream>>>(
        xs, Wih0, Whh0, Wih1, Whh1, Wcls, bih0, bhh0, bih1, bhh1,
        xbf, wih0b, whh0b, wih1b, whh1b, wclsb, bias0, bias1,
        h0a /*hzero base: h0a|h0b|h1a|h1b*/);

    {
        void* args[] = {
            (void*)&xbf, (void*)&wih0b, (void*)&whh0b, (void*)&wih1b,
            (void*)&whh1b, (void*)&bias0, (void*)&bias1,
            (void*)&h0a, (void*)&h0b, (void*)&h1a, (void*)&h1b, (void*)&h1f
        };
        hipLaunchCooperativeKernel((const void*)persist_kernel,
                                   dim3(256), dim3(512), args, 0, stream);
    }

    cls_kernel<<<63, 512, 0, stream>>>(h1f, du, wclsb, bcls, out);
}

// Round 5
// 827.390 us; speedup vs baseline: 3.9035x; 3.0944x over previous
//
#include <hip/hip_runtime.h>
#include <hip/hip_bf16.h>
#include <hip/hip_cooperative_groups.h>

// ---------------------------------------------------------------------------
// StackedLSTM (2-layer, 64 steps) + dropout + classifier on MI355X.
//
// r5 design: persistent kernel (256 blocks, cooperative launch for guaranteed
// co-residency) with NO grid.sync(). r4's counters showed 93% idle at 37.8us
// per phase: grid.sync's device-scope acquire/release = L2 writeback +
// invalidate each phase, making all operands L2-cold (FETCH 1.8MB/phase).
//
// Sync protocol (flags in ws, zeroed by prep each call):
//   role 0 (even blocks) step t: needs h0done[t-1]==128 (own prev) and
//     h0rel[t-16]==128 (ring slot free). Produces h0(t), bumps h0done[t].
//   role 1 (odd blocks)  step t: needs h0done[t]==128, h1done[t-1]==128.
//     Produces h1(t), bumps h1done[t] and h0rel[t] (releases h0(t)).
// h rings: h0 16 slots, h1 4 slots; slot(t) = (t+1)%R; slot 0 = zeros.
//
// Coherence WITHOUT L2 flushes (per-XCD L2s stay warm for xbf/weights):
//   - h stores: packed 4B agent-scope stores (sc0 sc1, write-through to L3)
//   - h loads:  inline-asm global_load_dwordx4 sc0 sc1 (bypass L2, hit L3),
//     batched 8 per s_waitcnt vmcnt(0); 8 waves/CU overlap the L3 latency
//   - flags: agent-scope atomicAdd / relaxed atomic spin loads (+ s_sleep)
//   - xbf / weights / biases: normal cached loads (read-only, L2-resident)
//
// GEMM structure identical to r4 (same MFMA order -> absmax unchanged):
// frag-linear layouts, weights staged once into LDS, eps LDS shuffle,
// fused LSTM epilogue, cell state + biases pinned in registers.
// ---------------------------------------------------------------------------

typedef __attribute__((ext_vector_type(8))) short s8v;   // 8 x bf16 (4 VGPR)
typedef __attribute__((ext_vector_type(4))) float f4v;   // fp32 accum frag
typedef unsigned short bfu;

#define BATCH 128
#define HID   1024
#define NSTEP 64
#define TDIM  128
#define DDIM  512
#define TSTART 55
#define HSLOT 131072                 // elements per h ring slot (128x1024)

__device__ __forceinline__ bfu f2bf(float f) {
    union { float f; unsigned int u; } v; v.f = f;
    unsigned int r = (v.u + 0x7FFFu + ((v.u >> 16) & 1u)) >> 16;  // RNE
    return (bfu)r;
}
__device__ __forceinline__ float sigm(float x) {
    return 1.f / (1.f + __expf(-x));
}

// 8 coherent (L2-bypass) 16B loads + drain. Chunk stride = 1KB (512 elems).
__device__ __forceinline__ void load8_sc(const bfu* p, s8v (&o)[8]) {
    const bfu* p2 = p + 2048;   // +4096 B
    asm volatile(
        "global_load_dwordx4 %0, %[a0], off sc0 sc1\n\t"
        "global_load_dwordx4 %1, %[a0], off offset:1024 sc0 sc1\n\t"
        "global_load_dwordx4 %2, %[a0], off offset:2048 sc0 sc1\n\t"
        "global_load_dwordx4 %3, %[a0], off offset:3072 sc0 sc1\n\t"
        "global_load_dwordx4 %4, %[a1], off sc0 sc1\n\t"
        "global_load_dwordx4 %5, %[a1], off offset:1024 sc0 sc1\n\t"
        "global_load_dwordx4 %6, %[a1], off offset:2048 sc0 sc1\n\t"
        "global_load_dwordx4 %7, %[a1], off offset:3072 sc0 sc1\n\t"
        "s_waitcnt vmcnt(0)"
        : "=&v"(o[0]), "=&v"(o[1]), "=&v"(o[2]), "=&v"(o[3]),
          "=&v"(o[4]), "=&v"(o[5]), "=&v"(o[6]), "=&v"(o[7])
        : [a0]"v"(p), [a1]"v"(p2)
        : "memory");
}

// ---------------------------------------------------------------------------
// prep: fp32->bf16 (x into frag layout), combined biases, zero ring slot 0
// of h0/h1 and the sync flags.
// ---------------------------------------------------------------------------
__global__ void prep_kernel(
    const float* __restrict__ xs,
    const float* __restrict__ Wih0, const float* __restrict__ Whh0,
    const float* __restrict__ Wih1, const float* __restrict__ Whh1,
    const float* __restrict__ Wcls,
    const float* __restrict__ bih0, const float* __restrict__ bhh0,
    const float* __restrict__ bih1, const float* __restrict__ bhh1,
    bfu* __restrict__ xbf, bfu* __restrict__ wih0b, bfu* __restrict__ whh0b,
    bfu* __restrict__ wih1b, bfu* __restrict__ whh1b, bfu* __restrict__ wclsb,
    float* __restrict__ bias0, float* __restrict__ bias1,
    bfu* __restrict__ h0ring, bfu* __restrict__ h1ring, int* __restrict__ flags)
{
    const size_t NX  = (size_t)NSTEP * BATCH * DDIM;         // 4,194,304
    const size_t E1  = NX  + (size_t)4096 * 512;             // +wih0
    const size_t E2  = E1  + (size_t)4096 * 1024;            // +whh0
    const size_t E3  = E2  + (size_t)4096 * 1024;            // +wih1
    const size_t E4  = E3  + (size_t)4096 * 1024;            // +whh1
    const size_t E5  = E4  + (size_t)1000 * 1024;            // +wcls
    const size_t E6  = E5  + 4096;                           // bias0
    const size_t E7  = E6  + 4096;                           // bias1
    const size_t E8  = E7  + HSLOT;                          // h0 slot 0
    const size_t E9  = E8  + HSLOT;                          // h1 slot 0
    const size_t E10 = E9  + 1024;                           // flags (int)

    size_t stride = (size_t)gridDim.x * blockDim.x;
    for (size_t i = (size_t)blockIdx.x * blockDim.x + threadIdx.x; i < E10; i += stride) {
        if (i < NX) {
            // destination is frag-permuted within each 65536-element step
            size_t t   = i >> 16;
            int    rem = (int)(i & 65535);
            int chunk = rem >> 9;          // 1KB chunk (512 elems)
            int le    = rem & 511;
            int l = le >> 3, e = le & 7;
            int m  = chunk >> 4;           // K=512 -> 16 chunks per M-tile
            int kk = chunk & 15;
            int row = m * 16 + (l & 15);
            int k   = kk * 32 + (l >> 4) * 8 + e;
            xbf[i] = f2bf(xs[(size_t)row * (TDIM * DDIM) + (TSTART + t) * DDIM + k]);
        } else if (i < E1) { size_t j = i - NX;  wih0b[j] = f2bf(Wih0[j]); }
        else if (i < E2)   { size_t j = i - E1;  whh0b[j] = f2bf(Whh0[j]); }
        else if (i < E3)   { size_t j = i - E2;  wih1b[j] = f2bf(Wih1[j]); }
        else if (i < E4)   { size_t j = i - E3;  whh1b[j] = f2bf(Whh1[j]); }
        else if (i < E5)   { size_t j = i - E4;  wclsb[j] = f2bf(Wcls[j]); }
        else if (i < E6)   { size_t j = i - E5;  bias0[j] = bih0[j] + bhh0[j]; }
        else if (i < E7)   { size_t j = i - E6;  bias1[j] = bih1[j] + bhh1[j]; }
        else if (i < E8)   { h0ring[i - E7] = 0; }
        else if (i < E9)   { h1ring[i - E8] = 0; }
        else               { flags[i - E9] = 0; }
    }
}

// ---------------------------------------------------------------------------
// One layer-step: gates = A1@W1^T + A2@W2^T (+bias), fused cell update.
// A1: frag-permuted, CH1 chunks/M-tile (normal loads if !SC1, coherent if SC1)
// A2: frag-permuted h (always coherent), 32 chunks/M-tile.
// W in LDS frag-linear: [G1 NT0: CH1][G1 NT1: CH1][G2 NT0: 32][G2 NT1: 32].
// D layout (m89/m91): row = w*16 + kg*4 + r, col = lr.
// ---------------------------------------------------------------------------
template<bool SC1, int CH1>
__device__ __forceinline__ void layer_step(
    const bfu* __restrict__ A1, const bfu* __restrict__ A2,
    const bfu* __restrict__ wlds, float (*eps)[33],
    bfu* __restrict__ h_out, float* __restrict__ h_out_f32,
    int tid, int n0, const float (&bg)[8], float& cA, float& cB)
{
    const int l  = tid & 63;
    const int w  = tid >> 6;       // wave id == M-tile
    const int lr = l & 15;
    const int kg = l >> 4;

    f4v acc0 = {0.f, 0.f, 0.f, 0.f};
    f4v acc1 = {0.f, 0.f, 0.f, 0.f};

    {   // GEMM1: A1 @ W1^T (CH1 chunks)
        const bfu* ap  = A1 + (size_t)(w * CH1) * 512 + l * 8;
        const bfu* b0p = wlds + l * 8;
        const bfu* b1p = wlds + (size_t)CH1 * 512 + l * 8;
        if constexpr (SC1) {
            #pragma unroll
            for (int g = 0; g < CH1 / 8; ++g) {
                s8v o[8];
                load8_sc(ap, o); ap += 8 * 512;
                #pragma unroll
                for (int c = 0; c < 8; ++c) {
                    s8v b0 = *(const s8v*)b0p; b0p += 512;
                    s8v b1 = *(const s8v*)b1p; b1p += 512;
                    acc0 = __builtin_amdgcn_mfma_f32_16x16x32_bf16(o[c], b0, acc0, 0, 0, 0);
                    acc1 = __builtin_amdgcn_mfma_f32_16x16x32_bf16(o[c], b1, acc1, 0, 0, 0);
                }
            }
        } else {
            #pragma unroll 8
            for (int kk = 0; kk < CH1; ++kk) {
                s8v a  = *(const s8v*)ap;  ap  += 512;
                s8v b0 = *(const s8v*)b0p; b0p += 512;
                s8v b1 = *(const s8v*)b1p; b1p += 512;
                acc0 = __builtin_amdgcn_mfma_f32_16x16x32_bf16(a, b0, acc0, 0, 0, 0);
                acc1 = __builtin_amdgcn_mfma_f32_16x16x32_bf16(a, b1, acc1, 0, 0, 0);
            }
        }
    }
    {   // GEMM2: A2 @ W2^T (32 chunks, K=1024, coherent)
        const bfu* ap  = A2 + (size_t)(w * 32) * 512 + l * 8;
        const bfu* b0p = wlds + (size_t)(2 * CH1) * 512 + l * 8;
        const bfu* b1p = wlds + (size_t)(2 * CH1 + 32) * 512 + l * 8;
        #pragma unroll
        for (int g = 0; g < 4; ++g) {
            s8v o[8];
            load8_sc(ap, o); ap += 8 * 512;
            #pragma unroll
            for (int c = 0; c < 8; ++c) {
                s8v b0 = *(const s8v*)b0p; b0p += 512;
                s8v b1 = *(const s8v*)b1p; b1p += 512;
                acc0 = __builtin_amdgcn_mfma_f32_16x16x32_bf16(o[c], b0, acc0, 0, 0, 0);
                acc1 = __builtin_amdgcn_mfma_f32_16x16x32_bf16(o[c], b1, acc1, 0, 0, 0);
            }
        }
    }

    {   // D -> eps
        const int rbase = w * 16 + kg * 4;
        #pragma unroll
        for (int r = 0; r < 4; ++r) {
            eps[rbase + r][lr]      = acc0[r];
            eps[rbase + r][16 + lr] = acc1[r];
        }
    }
    __syncthreads();

    // fused LSTM epilogue: thread owns (row = tid>>2, unit pair 2*(tid&3))
    {
        const int row = tid >> 2;
        const int up  = tid & 3;
        const int e0  = 2 * up;
        const int ne  = n0 + e0;
        float gi0 = eps[row][e0]          + bg[0];
        float gi1 = eps[row][e0 + 1]      + bg[1];
        float gf0 = eps[row][8 + e0]      + bg[2];
        float gf1 = eps[row][8 + e0 + 1]  + bg[3];
        float gg0 = eps[row][16 + e0]     + bg[4];
        float gg1 = eps[row][16 + e0 + 1] + bg[5];
        float go0 = eps[row][24 + e0]     + bg[6];
        float go1 = eps[row][24 + e0 + 1] + bg[7];
        float cn0 = sigm(gf0) * cA + sigm(gi0) * tanhf(gg0);
        float cn1 = sigm(gf1) * cB + sigm(gi1) * tanhf(gg1);
        cA = cn0; cB = cn1;
        float hn0 = sigm(go0) * tanhf(cn0);
        float hn1 = sigm(go1) * tanhf(cn1);
        // frag-permuted h write (K=1024 -> 32 chunks per M-tile), packed 4B,
        // agent-scope write-through (visible at L3 once vmcnt drains)
        const int idx = ((row >> 4) * 32 + (ne >> 5)) * 512
                      + (((ne >> 3) & 3) * 16 + (row & 15)) * 8 + (ne & 7);
        unsigned int pk = (unsigned int)f2bf(hn0) | ((unsigned int)f2bf(hn1) << 16);
        __hip_atomic_store((unsigned int*)(h_out + idx), pk,
                           __ATOMIC_RELAXED, __HIP_MEMORY_SCOPE_AGENT);
        if (h_out_f32) {
            h_out_f32[(size_t)row * HID + ne]     = hn0;
            h_out_f32[(size_t)row * HID + ne + 1] = hn1;
        }
    }
    asm volatile("s_waitcnt vmcnt(0)" ::: "memory");   // own stores at L3
    __syncthreads();                                   // all waves' stores done
}

// ---------------------------------------------------------------------------
// Persistent kernel. even blocks = layer0, odd = layer1; block owns 8 hidden
// units (32 gate cols). LDS: weights 96/128KB frag-linear + eps 16.9KB.
// ---------------------------------------------------------------------------
__global__ __launch_bounds__(512)
void persist_kernel(
    const bfu* __restrict__ xbf,
    const bfu* __restrict__ wih0, const bfu* __restrict__ whh0,
    const bfu* __restrict__ wih1, const bfu* __restrict__ whh1,
    const float* __restrict__ bias0, const float* __restrict__ bias1,
    bfu* __restrict__ h0ring, bfu* __restrict__ h1ring,
    float* __restrict__ h1f, int* __restrict__ flags)
{
    __shared__ bfu   wlds[65536];        // 128 KB
    __shared__ float eps[128][33];       // 16.9 KB

    const int tid  = threadIdx.x;
    const int role = blockIdx.x & 1;
    const int n0   = (blockIdx.x >> 1) * 8;

    int* h0done = flags;
    int* h1done = flags + 64;
    int* h0rel  = flags + 128;

    const bfu*   W1   = role ? wih1 : wih0;
    const bfu*   W2   = role ? whh1 : whh0;
    const float* bias = role ? bias1 : bias0;
    const int    K1   = role ? 1024 : 512;
    const int    CH1  = K1 >> 5;

    // ---- stage weights into LDS, frag-linear (once, normal cached loads) ----
    {
        const int units = (2 * CH1 + 64) * 64;   // 16B transfers
        for (int u0 = tid; u0 < units; u0 += 512) {
            const int c = u0 >> 6, l = u0 & 63;
            const int lr = l & 15, kg = l >> 4;
            const bfu* Wsrc; int K, nt, kk;
            if (c < 2 * CH1) { Wsrc = W1; K = K1;   nt = c / CH1; kk = c % CH1; }
            else { const int c2 = c - 2 * CH1; Wsrc = W2; K = 1024; nt = c2 >> 5; kk = c2 & 31; }
            const int cl = nt * 16 + lr;
            const int j  = (cl >> 3) * HID + n0 + (cl & 7);
            s8v v = *(const s8v*)(Wsrc + (size_t)j * K + kk * 32 + kg * 8);
            *(s8v*)(wlds + (size_t)c * 512 + l * 8) = v;
        }
    }
    __syncthreads();

    // ---- per-thread persistent epilogue state ----
    float bg[8];
    {
        const int ne = n0 + 2 * (tid & 3);
        bg[0] = bias[ne];             bg[1] = bias[ne + 1];
        bg[2] = bias[HID + ne];       bg[3] = bias[HID + ne + 1];
        bg[4] = bias[2 * HID + ne];   bg[5] = bias[2 * HID + ne + 1];
        bg[6] = bias[3 * HID + ne];   bg[7] = bias[3 * HID + ne + 1];
    }
    float cA = 0.f, cB = 0.f;

    if (role == 0) {
        for (int t = 0; t < NSTEP; ++t) {
            if (tid == 0) {
                if (t > 0)
                    while (__hip_atomic_load(&h0done[t - 1], __ATOMIC_RELAXED,
                                             __HIP_MEMORY_SCOPE_AGENT) < 128)
                        __builtin_amdgcn_s_sleep(1);
                if (t >= 16)
                    while (__hip_atomic_load(&h0rel[t - 16], __ATOMIC_RELAXED,
                                             __HIP_MEMORY_SCOPE_AGENT) < 128)
                        __builtin_amdgcn_s_sleep(1);
            }
            __syncthreads();
            const bfu* h0prev = h0ring + (size_t)(t & 15) * HSLOT;
            bfu*       h0cur  = h0ring + (size_t)((t + 1) & 15) * HSLOT;
            layer_step<false, 16>(xbf + (size_t)t * 65536, h0prev, wlds, eps,
                                  h0cur, nullptr, tid, n0, bg, cA, cB);
            if (tid == 0)
                __hip_atomic_fetch_add(&h0done[t], 1, __ATOMIC_RELAXED,
                                       __HIP_MEMORY_SCOPE_AGENT);
        }
    } else {
        for (int t = 0; t < NSTEP; ++t) {
            if (tid == 0) {
                while (__hip_atomic_load(&h0done[t], __ATOMIC_RELAXED,
                                         __HIP_MEMORY_SCOPE_AGENT) < 128)
                    __builtin_amdgcn_s_sleep(1);
                if (t > 0)
                    while (__hip_atomic_load(&h1done[t - 1], __ATOMIC_RELAXED,
                                             __HIP_MEMORY_SCOPE_AGENT) < 128)
                        __builtin_amdgcn_s_sleep(1);
            }
            __syncthreads();
            const bfu* h0t    = h0ring + (size_t)((t + 1) & 15) * HSLOT;
            const bfu* h1prev = h1ring + (size_t)(t & 3) * HSLOT;
            bfu*       h1cur  = h1ring + (size_t)((t + 1) & 3) * HSLOT;
            layer_step<true, 32>(h0t, h1prev, wlds, eps,
                                 h1cur, (t == NSTEP - 1) ? h1f : nullptr,
                                 tid, n0, bg, cA, cB);
            if (tid == 0) {
                __hip_atomic_fetch_add(&h1done[t], 1, __ATOMIC_RELAXED,
                                       __HIP_MEMORY_SCOPE_AGENT);
                __hip_atomic_fetch_add(&h0rel[t], 1, __ATOMIC_RELAXED,
                                       __HIP_MEMORY_SCOPE_AGENT);
            }
        }
    }
}

// ---------------------------------------------------------------------------
// classifier with fused dropout: out = (mask(h1)/0.5) @ Wcls^T + b_cls
// ---------------------------------------------------------------------------
__global__ __launch_bounds__(512)
void cls_kernel(const float* __restrict__ h1f, const float* __restrict__ du,
                const bfu* __restrict__ Wc, const float* __restrict__ bc,
                float* __restrict__ out)
{
    const int tid = threadIdx.x;
    const int l   = tid & 63;
    const int w   = tid >> 6;
    const int lr  = l & 15;
    const int kg  = l >> 4;
    const int j   = blockIdx.x * 16 + lr;
    const int jW  = (j < 1000) ? j : 999;   // clamp to stay in-bounds

    f4v acc = {0.f, 0.f, 0.f, 0.f};
    const float* hp = h1f + (size_t)(w * 16 + lr) * HID + kg * 8;
    const float* dp = du  + (size_t)(w * 16 + lr) * HID + kg * 8;
    const bfu*   bp = Wc  + (size_t)jW * HID + kg * 8;
    #pragma unroll 4
    for (int kk = 0; kk < HID; kk += 32) {
        f4v h0v = *(const f4v*)hp;
        f4v h1v = *(const f4v*)(hp + 4);
        f4v d0v = *(const f4v*)dp;
        f4v d1v = *(const f4v*)(dp + 4);
        s8v a;
        #pragma unroll
        for (int e = 0; e < 4; ++e) {
            a[e]     = (short)f2bf(d0v[e] > 0.5f ? h0v[e] * 2.f : 0.f);
            a[4 + e] = (short)f2bf(d1v[e] > 0.5f ? h1v[e] * 2.f : 0.f);
        }
        s8v b = *(const s8v*)bp;
        acc = __builtin_amdgcn_mfma_f32_16x16x32_bf16(a, b, acc, 0, 0, 0);
        hp += 32; dp += 32; bp += 32;
    }
    if (j < 1000) {
        const float bj = bc[j];
        const int rbase = w * 16 + kg * 4;
        #pragma unroll
        for (int r = 0; r < 4; ++r)
            out[(size_t)(rbase + r) * 1000 + j] = acc[r] + bj;
    }
}

// ---------------------------------------------------------------------------
extern "C" void kernel_launch(void* const* d_in, const int* in_sizes, int n_in,
                              void* d_out, int out_size, void* d_ws, size_t ws_size,
                              hipStream_t stream)
{
    const float* xs   = (const float*)d_in[0];
    const float* Wih0 = (const float*)d_in[1];
    const float* Whh0 = (const float*)d_in[2];
    const float* bih0 = (const float*)d_in[3];
    const float* bhh0 = (const float*)d_in[4];
    const float* Wih1 = (const float*)d_in[5];
    const float* Whh1 = (const float*)d_in[6];
    const float* bih1 = (const float*)d_in[7];
    const float* bhh1 = (const float*)d_in[8];
    const float* Wcls = (const float*)d_in[9];
    const float* bcls = (const float*)d_in[10];
    const float* du   = (const float*)d_in[11];
    float* out = (float*)d_out;

    // ws carve-out (256B-aligned), ~28 MB total
    char* p = (char*)d_ws;
    auto alloc = [&](size_t bytes) {
        char* r = p; p += (bytes + 255) & ~(size_t)255; return r;
    };
    bfu*   xbf   = (bfu*)  alloc((size_t)NSTEP * BATCH * DDIM * 2);
    bfu*   wih0b = (bfu*)  alloc((size_t)4096 * 512 * 2);
    bfu*   whh0b = (bfu*)  alloc((size_t)4096 * 1024 * 2);
    bfu*   wih1b = (bfu*)  alloc((size_t)4096 * 1024 * 2);
    bfu*   whh1b = (bfu*)  alloc((size_t)4096 * 1024 * 2);
    bfu*   wclsb = (bfu*)  alloc((size_t)1000 * 1024 * 2);
    float* bias0 = (float*)alloc(4096 * 4);
    float* bias1 = (float*)alloc(4096 * 4);
    bfu*   h0ring = (bfu*) alloc((size_t)16 * HSLOT * 2);   // 16 slots
    bfu*   h1ring = (bfu*) alloc((size_t)4 * HSLOT * 2);    // 4 slots
    float* h1f    = (float*)alloc((size_t)BATCH * HID * 4);
    int*   flags  = (int*) alloc(1024 * 4);
    (void)ws_size; (void)in_sizes; (void)n_in; (void)out_size;

    prep_kernel<<<2048, 256, 0, stream>>>(
        xs, Wih0, Whh0, Wih1, Whh1, Wcls, bih0, bhh0, bih1, bhh1,
        xbf, wih0b, whh0b, wih1b, whh1b, wclsb, bias0, bias1,
        h0ring, h1ring, flags);

    {
        void* args[] = {
            (void*)&xbf, (void*)&wih0b, (void*)&whh0b, (void*)&wih1b,
            (void*)&whh1b, (void*)&bias0, (void*)&bias1,
            (void*)&h0ring, (void*)&h1ring, (void*)&h1f, (void*)&flags
        };
        hipLaunchCooperativeKernel((const void*)persist_kernel,
                                   dim3(256), dim3(512), args, 0, stream);
    }

    cls_kernel<<<63, 512, 0, stream>>>(h1f, du, wclsb, bcls, out);
}